// Round 3
// baseline (305.771 us; speedup 1.0000x reference)
//
#include <hip/hip_runtime.h>
#include <math.h>

#define NT 16384
#define DIM 2048
#define NE 64
#define TK 8

typedef _Float16 f16_t;
typedef _Float16 half8 __attribute__((ext_vector_type(8)));
typedef float floatx16 __attribute__((ext_vector_type(16)));

// ---------------- Prep: W fp32 -> f16 hi/lo in 32x32x16 B-fragment order; block 64 = scalar chain ----------------
// B-frag layout (verified): lane holds B[n=lane&31][k=8*(lane>>5)+j], one 16B half8 per frag.
__global__ __launch_bounds__(256) void prep_kernel(const float* __restrict__ w,
                                                   const float* __restrict__ expert_loads,
                                                   const float* __restrict__ bias_strength,
                                                   float* __restrict__ ws_bias,
                                                   float* __restrict__ ws_batch,
                                                   unsigned int* __restrict__ ws_counter,
                                                   f16_t* __restrict__ whi,
                                                   f16_t* __restrict__ wlo,
                                                   float* __restrict__ out_bias_strength) {
    if (blockIdx.x == 64) {
        int e = threadIdx.x;
        if (e < 64) {
            float load = expert_loads[e];
            float s = load;
            #pragma unroll
            for (int off = 32; off >= 1; off >>= 1) s += __shfl_xor(s, off, 64);
            s = fmaxf(s, 1e-8f);
            float q = load / s;
            const float t = 1.0f / 64.0f;
            float kl = t * (logf(t) - logf(fmaxf(q, 1e-8f)));
            #pragma unroll
            for (int off = 32; off >= 1; off >>= 1) kl += __shfl_xor(kl, off, 64);
            float as = 1.0f / (1.0f + expf(-10.0f * kl));
            float nbs = 0.9f * bias_strength[0] + 0.1f * as;
            ws_bias[e] = tanhf((q - t) * 64.0f) * nbs;
            ws_batch[e] = 0.0f;
            if (e == 0) { out_bias_strength[0] = nbs; ws_counter[0] = 0u; }
        }
        return;
    }
    int idx = blockIdx.x * 256 + threadIdx.x;   // (c16, tile, lane)
    int lane = idx & 63;
    int tile = (idx >> 6) & 1;
    int c    = idx >> 7;
    int n = tile * 32 + (lane & 31);
    int k = c * 16 + (lane >> 5) * 8;
    const float* src = w + (size_t)n * DIM + k;
    float4 a = *(const float4*)src;
    float4 b = *(const float4*)(src + 4);
    float v[8] = {a.x, a.y, a.z, a.w, b.x, b.y, b.z, b.w};
    half8 h, l;
    #pragma unroll
    for (int j = 0; j < 8; ++j) {
        f16_t hh = (f16_t)v[j];
        h[j] = hh;
        l[j] = (f16_t)(v[j] - (float)hh);
    }
    *(half8*)(whi + (size_t)idx * 8) = h;
    *(half8*)(wlo + (size_t)idx * 8) = l;
}

// ---------------- Main: async gload_lds double-buffered split-f16 MFMA GEMM + noise + bias + top-8 + fused EMA --
// 512 thr = 8 waves = split-K x8. Tile 32 tokens x 64 experts. Grid 512 = 2 blocks/CU, 4 waves/SIMD.
// (ROUND-1 VERIFIED STRUCTURE — round 2's direct-register loads were 32x uncoalesced per-instr and regressed.)
// Pipeline: raw fp32 staged by global_load_lds width=16 (wave reads contiguous 1KB row segments -> perfectly
// coalesced), 2 LDS buffers, raw s_barrier + counted vmcnt (never __syncthreads in the K-loop).
// B-frag loads issued BEFORE STAGE(s+1) so in-order vmcnt retirement gives:
//   outstanding at wait = [4 gload(s) old] [8 B-frag] [4 gload(s+1) new] -> vmcnt(12) retires window s only,
// and the compiler's pre-MFMA wait for B-frags lands at vmcnt(4), keeping the prefetch in flight.
__global__ __launch_bounds__(512, 4) void router_main(const float* __restrict__ x,
                                                      const f16_t* __restrict__ whi,
                                                      const f16_t* __restrict__ wlo,
                                                      const float* __restrict__ noise,
                                                      const float* __restrict__ ws_bias,
                                                      float* __restrict__ ws_batch,
                                                      unsigned int* __restrict__ ws_counter,
                                                      const float* __restrict__ expert_loads,
                                                      float* __restrict__ out) {
    // 69,632 B: stage[2][32][260] f32 (66,560 B) overlaid by part[8][32][68] f32 afterwards
    __shared__ float smem[17408];
    __shared__ float bias_sh[64];
    __shared__ float loads_sh[64];
    __shared__ int last_flag;

    const int tid = threadIdx.x;
    const int wv  = tid >> 6;        // 0..7: split-K partition (chunks s*16 + wv*2 + {0,1})
    const int L   = tid & 63;
    const int r   = L & 31;          // A-frag row (token within tile)
    const int kh  = L >> 5;
    const int token0 = blockIdx.x * 32;

    if (tid < 64) { bias_sh[tid] = ws_bias[tid]; loads_sh[tid] = 0.0f; }
    if (tid == 0) last_flag = 0;

    const half8* whi8 = (const half8*)whi;
    const half8* wlo8 = (const half8*)wlo;

    floatx16 acc0, acc1;
    #pragma unroll
    for (int i = 0; i < 16; ++i) { acc0[i] = 0.0f; acc1[i] = 0.0f; }

    // Issue one window (32 rows x 1KB) of raw fp32 into LDS buffer S&1.
    // Dest is wave-uniform row base + lane*16B (gload_lds constraint); row stride 260 f32 = 1040 B.
    auto STAGE = [&](int S) {
        const int b_ = S & 1;
        #pragma unroll
        for (int q = 0; q < 4; ++q) {
            const int row_ = wv + q * 8;
            const float* gsrc = x + (size_t)(token0 + row_) * DIM + S * 256 + L * 4;
            float* ldst = (float*)(smem + b_ * 8320 + row_ * 260);
            __builtin_amdgcn_global_load_lds(
                (const __attribute__((address_space(1))) unsigned int*)gsrc,
                (__attribute__((address_space(3))) unsigned int*)ldst,
                16, 0, 0);
        }
    };

    STAGE(0);

    #pragma unroll
    for (int s = 0; s < 8; ++s) {
        // B fragments for this window's two chunks (L2-resident, 8 x 16B). MUST precede STAGE(s+1).
        half8 bf[8];
        {
            const int c0 = s * 16 + wv * 2;
            const int i0 = (c0 * 2) * 64 + L;
            const int i1 = ((c0 + 1) * 2) * 64 + L;
            bf[0] = whi8[i0];      bf[1] = whi8[i0 + 64];
            bf[2] = wlo8[i0];      bf[3] = wlo8[i0 + 64];
            bf[4] = whi8[i1];      bf[5] = whi8[i1 + 64];
            bf[6] = wlo8[i1];      bf[7] = wlo8[i1 + 64];
        }
        if (s < 7) {
            STAGE(s + 1);
            asm volatile("s_waitcnt vmcnt(12)" ::: "memory");  // window-s gloads retired; 8 B + 4 prefetch alive
        } else {
            asm volatile("s_waitcnt vmcnt(8)" ::: "memory");   // last window: only 8 B-frags newer
        }
        __builtin_amdgcn_sched_barrier(0);
        __builtin_amdgcn_s_barrier();        // (A) all waves' window-s rows visible

        const float* xrow = smem + (s & 1) * 8320 + r * 260 + wv * 32 + kh * 8;
        #pragma unroll
        for (int cc = 0; cc < 2; ++cc) {
            float4 f0 = *(const float4*)(xrow + cc * 16);
            float4 f1 = *(const float4*)(xrow + cc * 16 + 4);
            float v[8] = {f0.x, f0.y, f0.z, f0.w, f1.x, f1.y, f1.z, f1.w};
            half8 ah, al;
            #pragma unroll
            for (int j = 0; j < 8; ++j) {
                f16_t hh = (f16_t)v[j];              // RNE hi (verified numerics)
                ah[j] = hh;
                al[j] = (f16_t)(v[j] - (float)hh);   // RNE lo
            }
            acc0 = __builtin_amdgcn_mfma_f32_32x32x16_f16(ah, bf[cc * 4 + 0], acc0, 0, 0, 0);
            acc1 = __builtin_amdgcn_mfma_f32_32x32x16_f16(ah, bf[cc * 4 + 1], acc1, 0, 0, 0);
            acc0 = __builtin_amdgcn_mfma_f32_32x32x16_f16(al, bf[cc * 4 + 0], acc0, 0, 0, 0);
            acc1 = __builtin_amdgcn_mfma_f32_32x32x16_f16(al, bf[cc * 4 + 1], acc1, 0, 0, 0);
            acc0 = __builtin_amdgcn_mfma_f32_32x32x16_f16(ah, bf[cc * 4 + 2], acc0, 0, 0, 0);
            acc1 = __builtin_amdgcn_mfma_f32_32x32x16_f16(ah, bf[cc * 4 + 3], acc1, 0, 0, 0);
        }
        __builtin_amdgcn_s_barrier();        // (B) buf[s&1] fully consumed -> STAGE(s+2) may overwrite
    }

    // Last barrier (B) guarantees all staging reads done; reuse staging region as part[].
    // C/D layout (verified m74/m101): col=lane&31, row=(reg&3)+8*(reg>>2)+4*kh
    #pragma unroll
    for (int reg = 0; reg < 16; ++reg) {
        int row = (reg & 3) + 8 * (reg >> 2) + 4 * kh;
        smem[wv * 2176 + row * 68 + r]      = acc0[reg];
        smem[wv * 2176 + row * 68 + 32 + r] = acc1[reg];
    }
    __syncthreads();

    // Split-K reduce + noise + bias -> final logits into part[0]
    #pragma unroll
    for (int p = 0; p < 4; ++p) {
        int o = tid + p * 512;               // 0..2047
        int t = o >> 6, e = o & 63;
        float sum = 0.0f;
        #pragma unroll
        for (int q = 0; q < 8; ++q) sum += smem[q * 2176 + t * 68 + e];
        sum += noise[(size_t)(token0 + t) * NE + e] * 0.01f - bias_sh[e];
        smem[t * 68 + e] = sum;              // own slot; no cross-thread hazard
    }
    __syncthreads();

    // Top-8 (strict '>' keeps lower index on ties, matching jax.lax.top_k) + softmax + load scatter
    if (tid < 32) {
        int t = tid;
        float tv[TK]; int ti_[TK];
        #pragma unroll
        for (int j = 0; j < TK; ++j) { tv[j] = -INFINITY; ti_[j] = 0; }
        for (int e = 0; e < NE; ++e) {
            float v = smem[t * 68 + e]; int id = e;
            #pragma unroll
            for (int j = 0; j < TK; ++j) {
                bool gt = v > tv[j];
                float nv = gt ? v : tv[j];
                int   ni = gt ? id : ti_[j];
                float ov = gt ? tv[j] : v;
                int   oi = gt ? ti_[j] : id;
                tv[j] = nv; ti_[j] = ni; v = ov; id = oi;
            }
        }
        float m = tv[0], ssum = 0.0f, wvv[TK];
        #pragma unroll
        for (int j = 0; j < TK; ++j) { wvv[j] = expf(tv[j] - m); ssum += wvv[j]; }
        float inv = 1.0f / ssum;
        size_t gt_ = (size_t)(token0 + t);
        #pragma unroll
        for (int j = 0; j < TK; ++j) {
            float wgt = wvv[j] * inv;
            out[gt_ * TK + j] = (float)ti_[j];
            out[(size_t)NT * TK + gt_ * TK + j] = wgt;
            atomicAdd(&loads_sh[ti_[j]], wgt);
        }
    }
    __syncthreads();
    if (tid < 64) atomicAdd(&ws_batch[tid], loads_sh[tid]);

    // ---- fused EMA finalize: last block to finish does it (device-scope counter; verified round 2) ----
    __threadfence();                          // ws_batch adds visible device-wide before counter bump
    if (tid == 0) {
        unsigned int prev = atomicAdd(ws_counter, 1u);
        if (prev == (unsigned int)(NT / 32 - 1)) last_flag = 1;
    }
    __syncthreads();
    if (last_flag && tid < 64) {
        float bl = atomicAdd(&ws_batch[tid], 0.0f);   // coherent read (cross-XCD safe)
        out[(size_t)NT * TK * 2 + tid] = 0.999f * expert_loads[tid] + 0.001f * (bl / (float)NT);
    }
}

extern "C" void kernel_launch(void* const* d_in, const int* in_sizes, int n_in,
                              void* d_out, int out_size, void* d_ws, size_t ws_size,
                              hipStream_t stream) {
    const float* x     = (const float*)d_in[0];  // [16384, 2048]
    const float* rw    = (const float*)d_in[1];  // [64, 2048]
    const float* loads = (const float*)d_in[2];  // [64]
    const float* bs    = (const float*)d_in[3];  // [1]
    const float* noise = (const float*)d_in[4];  // [16384, 64]
    float* out = (float*)d_out;                  // [131072 idx | 131072 w | 64 loads | 1 bias]
    float* ws  = (float*)d_ws;
    float* ws_bias  = ws;                        // [64]
    float* ws_batch = ws + 64;                   // [64]
    unsigned int* ws_counter = (unsigned int*)(ws + 128);
    f16_t* whi = (f16_t*)(ws + 160);             // 16384 frags x 8 halves = 256 KB (16B aligned)
    f16_t* wlo = whi + (size_t)16384 * 8;        // another 256 KB

    prep_kernel<<<65, 256, 0, stream>>>(rw, loads, bs, ws_bias, ws_batch, ws_counter, whi, wlo,
                                        out + (size_t)NT * TK * 2 + NE);
    router_main<<<NT / 32, 512, 0, stream>>>(x, whi, wlo, noise, ws_bias, ws_batch, ws_counter,
                                             loads, out);
}

// Round 4
// 216.449 us; speedup vs baseline: 1.4127x; 1.4127x over previous
//
#include <hip/hip_runtime.h>
#include <math.h>

#define NT 16384
#define DIM 2048
#define NE 64
#define TK 8

typedef _Float16 f16_t;
typedef _Float16 half8 __attribute__((ext_vector_type(8)));
typedef float floatx16 __attribute__((ext_vector_type(16)));

// ---------------- Prep: W fp32 -> f16 hi/lo in 32x32x16 B-fragment order; block 64 = scalar chain ----------------
// B-frag layout (verified): lane holds B[n=lane&31][k=8*(lane>>5)+j], one 16B half8 per frag.
__global__ __launch_bounds__(256) void prep_kernel(const float* __restrict__ w,
                                                   const float* __restrict__ expert_loads,
                                                   const float* __restrict__ bias_strength,
                                                   float* __restrict__ ws_bias,
                                                   float* __restrict__ ws_batch,
                                                   f16_t* __restrict__ whi,
                                                   f16_t* __restrict__ wlo,
                                                   float* __restrict__ out_bias_strength) {
    if (blockIdx.x == 64) {
        int e = threadIdx.x;
        if (e < 64) {
            float load = expert_loads[e];
            float s = load;
            #pragma unroll
            for (int off = 32; off >= 1; off >>= 1) s += __shfl_xor(s, off, 64);
            s = fmaxf(s, 1e-8f);
            float q = load / s;
            const float t = 1.0f / 64.0f;
            float kl = t * (logf(t) - logf(fmaxf(q, 1e-8f)));
            #pragma unroll
            for (int off = 32; off >= 1; off >>= 1) kl += __shfl_xor(kl, off, 64);
            float as = 1.0f / (1.0f + expf(-10.0f * kl));
            float nbs = 0.9f * bias_strength[0] + 0.1f * as;
            ws_bias[e] = tanhf((q - t) * 64.0f) * nbs;
            ws_batch[e] = 0.0f;
            if (e == 0) out_bias_strength[0] = nbs;
        }
        return;
    }
    int idx = blockIdx.x * 256 + threadIdx.x;   // (c16, tile, lane)
    int lane = idx & 63;
    int tile = (idx >> 6) & 1;
    int c    = idx >> 7;
    int n = tile * 32 + (lane & 31);
    int k = c * 16 + (lane >> 5) * 8;
    const float* src = w + (size_t)n * DIM + k;
    float4 a = *(const float4*)src;
    float4 b = *(const float4*)(src + 4);
    float v[8] = {a.x, a.y, a.z, a.w, b.x, b.y, b.z, b.w};
    half8 h, l;
    #pragma unroll
    for (int j = 0; j < 8; ++j) {
        f16_t hh = (f16_t)v[j];
        h[j] = hh;
        l[j] = (f16_t)(v[j] - (float)hh);
    }
    *(half8*)(whi + (size_t)idx * 8) = h;
    *(half8*)(wlo + (size_t)idx * 8) = l;
}

// ---------------- Main: BARRIER-FREE wave-private split-f16 MFMA GEMM + noise + bias + top-8 + softmax ----------
// 512 thr = 8 waves. Wave wv owns the CONTIGUOUS K-segment cols [wv*256, wv*256+256) -> staging is wave-private:
// each wave double-buffers its own 2 x 4KB LDS region (8 waves x 8KB = 64KB, overlaid by part[] afterwards).
// NO s_barrier in the K-loop: per-wave counted vmcnt(12) is the only sync (gload_lds retirement = LDS write done,
// and the wave consumes only its own buffer). 16 waves/CU self-pace -> no lockstep latency exposure.
// LDS swizzle (T21: pre-permuted GLOBAL src + swizzled read; gload_lds dest stays linear):
//   logical (row r, 16B-unit u) stored at phys unit r*8 + (u ^ (r&7)); staging lane L of instr q supplies
//   row q*8+(L>>3), unit (L&7)^((L>>3)&7) -> same 128B line per lane-octet (fully coalesced); consume reads
//   unit (kh*2+cc*4)^ (r&7) and ^1 -> <=4-way bank conflict instead of 32-way.
// FP math per chunk identical to verified kernel (RNE hi/lo split, 6-MFMA order); split-K grouping is contiguous
// (wave wv sums chunks wv*16..wv*16+15) -- reorder noise ~2^-20, invisible under the 1e-3 split-f16 tolerance.
__global__ __launch_bounds__(512, 4) void router_main(const float* __restrict__ x,
                                                      const f16_t* __restrict__ whi,
                                                      const f16_t* __restrict__ wlo,
                                                      const float* __restrict__ noise,
                                                      const float* __restrict__ ws_bias,
                                                      float* __restrict__ ws_batch,
                                                      float* __restrict__ out) {
    // 69,632 B: stage[8 waves][2 bufs][1024 f32] (65,536 B) overlaid by part[8][32][68] f32 afterwards
    __shared__ float smem[17408];
    __shared__ float bias_sh[64];
    __shared__ float loads_sh[64];

    const int tid = threadIdx.x;
    const int wv  = tid >> 6;        // 0..7: owns cols [wv*256, wv*256+256)
    const int L   = tid & 63;
    const int r   = L & 31;          // A-frag row (token within tile)
    const int kh  = L >> 5;
    const int sw  = r & 7;           // per-lane swizzle key
    const int token0 = blockIdx.x * 32;

    if (tid < 64) { bias_sh[tid] = ws_bias[tid]; loads_sh[tid] = 0.0f; }

    // Noise prefetch: one float4/thread, held in VGPRs across the GEMM (reduce re-indexed to match).
    float4 nz = *(const float4*)(noise + (size_t)token0 * NE + tid * 4);

    const half8* whi8 = (const half8*)whi;
    const half8* wlo8 = (const half8*)wlo;

    floatx16 acc0, acc1;
    #pragma unroll
    for (int i = 0; i < 16; ++i) { acc0[i] = 0.0f; acc1[i] = 0.0f; }

    // Stage window S (32 rows x 32 cols of this wave's segment) into wave-private buffer S&1.
    // ldst is wave-uniform (gload_lds writes base + lane*16); gsrc carries the per-lane swizzle.
    auto STAGE = [&](int S) {
        const int b_ = S & 1;
        #pragma unroll
        for (int q = 0; q < 4; ++q) {
            const float* gsrc = x + (size_t)(token0 + q * 8 + (L >> 3)) * DIM
                                  + wv * 256 + S * 32 + (((L & 7) ^ ((L >> 3) & 7)) << 2);
            float* ldst = (float*)(smem + wv * 2048 + b_ * 1024 + q * 256);
            __builtin_amdgcn_global_load_lds(
                (const __attribute__((address_space(1))) unsigned int*)gsrc,
                (__attribute__((address_space(3))) unsigned int*)ldst,
                16, 0, 0);
        }
    };

    STAGE(0);

    #pragma unroll
    for (int s = 0; s < 8; ++s) {
        // B fragments for this wave's two chunks of window s (L2-resident, 8 x 16B). Issued before STAGE(s+1)
        // so the compiler's pre-MFMA wait lands at vmcnt(4), keeping the prefetch in flight.
        half8 bf[8];
        {
            const int c0 = wv * 16 + s * 2;
            const int i0 = (c0 * 2) * 64 + L;
            const int i1 = ((c0 + 1) * 2) * 64 + L;
            bf[0] = whi8[i0];      bf[1] = whi8[i0 + 64];
            bf[2] = wlo8[i0];      bf[3] = wlo8[i0 + 64];
            bf[4] = whi8[i1];      bf[5] = whi8[i1 + 64];
            bf[6] = wlo8[i1];      bf[7] = wlo8[i1 + 64];
        }
        if (s < 7) {
            STAGE(s + 1);
            asm volatile("s_waitcnt vmcnt(12)" ::: "memory");  // window-s stage retired; 8 B-frag + 4 prefetch alive
        } else {
            asm volatile("s_waitcnt vmcnt(8)" ::: "memory");   // last window: only 8 B-frags newer
        }
        // NO barrier: this wave reads only its own buffer.

        const float* wb = smem + wv * 2048 + (s & 1) * 1024;
        #pragma unroll
        for (int cc = 0; cc < 2; ++cc) {
            const int u  = kh * 2 + cc * 4;            // even logical unit
            const int pu = (u ^ sw);
            float4 f0 = *(const float4*)(wb + r * 32 + (pu << 2));
            float4 f1 = *(const float4*)(wb + r * 32 + ((pu ^ 1) << 2));
            float v[8] = {f0.x, f0.y, f0.z, f0.w, f1.x, f1.y, f1.z, f1.w};
            half8 ah, al;
            #pragma unroll
            for (int j = 0; j < 8; ++j) {
                f16_t hh = (f16_t)v[j];              // RNE hi (verified numerics)
                ah[j] = hh;
                al[j] = (f16_t)(v[j] - (float)hh);   // RNE lo
            }
            acc0 = __builtin_amdgcn_mfma_f32_32x32x16_f16(ah, bf[cc * 4 + 0], acc0, 0, 0, 0);
            acc1 = __builtin_amdgcn_mfma_f32_32x32x16_f16(ah, bf[cc * 4 + 1], acc1, 0, 0, 0);
            acc0 = __builtin_amdgcn_mfma_f32_32x32x16_f16(al, bf[cc * 4 + 0], acc0, 0, 0, 0);
            acc1 = __builtin_amdgcn_mfma_f32_32x32x16_f16(al, bf[cc * 4 + 1], acc1, 0, 0, 0);
            acc0 = __builtin_amdgcn_mfma_f32_32x32x16_f16(ah, bf[cc * 4 + 2], acc0, 0, 0, 0);
            acc1 = __builtin_amdgcn_mfma_f32_32x32x16_f16(ah, bf[cc * 4 + 3], acc1, 0, 0, 0);
        }
    }

    __syncthreads();   // ONLY block-wide sync before epilogue: all waves done with stage region -> reuse as part[]

    // C/D layout (verified m74/m101): col=lane&31, row=(reg&3)+8*(reg>>2)+4*kh
    #pragma unroll
    for (int reg = 0; reg < 16; ++reg) {
        int row = (reg & 3) + 8 * (reg >> 2) + 4 * kh;
        smem[wv * 2176 + row * 68 + r]      = acc0[reg];
        smem[wv * 2176 + row * 68 + 32 + r] = acc1[reg];
    }
    __syncthreads();

    // Split-K reduce + noise + bias -> final logits into part[0]. Thread tid owns o = tid*4+j (matches nz).
    float nzv[4] = {nz.x, nz.y, nz.z, nz.w};
    #pragma unroll
    for (int j = 0; j < 4; ++j) {
        int o = tid * 4 + j;                 // 0..2047
        int t = o >> 6, e = o & 63;
        float sum = 0.0f;
        #pragma unroll
        for (int q = 0; q < 8; ++q) sum += smem[q * 2176 + t * 68 + e];
        sum += nzv[j] * 0.01f - bias_sh[e];
        smem[t * 68 + e] = sum;              // own slot; no cross-thread hazard
    }
    __syncthreads();

    // Top-8 (strict '>' keeps lower index on ties, matching jax.lax.top_k) + softmax + load scatter
    if (tid < 32) {
        int t = tid;
        float tv[TK]; int ti_[TK];
        #pragma unroll
        for (int j = 0; j < TK; ++j) { tv[j] = -INFINITY; ti_[j] = 0; }
        for (int e = 0; e < NE; ++e) {
            float v = smem[t * 68 + e]; int id = e;
            #pragma unroll
            for (int j = 0; j < TK; ++j) {
                bool gt = v > tv[j];
                float nv = gt ? v : tv[j];
                int   ni = gt ? id : ti_[j];
                float ov = gt ? tv[j] : v;
                int   oi = gt ? ti_[j] : id;
                tv[j] = nv; ti_[j] = ni; v = ov; id = oi;
            }
        }
        float m = tv[0], ssum = 0.0f, wvv[TK];
        #pragma unroll
        for (int j = 0; j < TK; ++j) { wvv[j] = expf(tv[j] - m); ssum += wvv[j]; }
        float inv = 1.0f / ssum;
        size_t gt_ = (size_t)(token0 + t);
        #pragma unroll
        for (int j = 0; j < TK; ++j) {
            float wgt = wvv[j] * inv;
            out[gt_ * TK + j] = (float)ti_[j];
            out[(size_t)NT * TK + gt_ * TK + j] = wgt;
            atomicAdd(&loads_sh[ti_[j]], wgt);
        }
    }
    __syncthreads();
    if (tid < 64) atomicAdd(&ws_batch[tid], loads_sh[tid]);
}

// ---------------- EMA load update (separate kernel; fused version's __threadfence caused ~90us L2-flush tail) --
__global__ __launch_bounds__(64) void finalize_kernel(const float* __restrict__ expert_loads,
                                                      const float* __restrict__ ws_batch,
                                                      float* __restrict__ out_loads) {
    int e = threadIdx.x;
    out_loads[e] = 0.999f * expert_loads[e] + 0.001f * (ws_batch[e] / (float)NT);
}

extern "C" void kernel_launch(void* const* d_in, const int* in_sizes, int n_in,
                              void* d_out, int out_size, void* d_ws, size_t ws_size,
                              hipStream_t stream) {
    const float* x     = (const float*)d_in[0];  // [16384, 2048]
    const float* rw    = (const float*)d_in[1];  // [64, 2048]
    const float* loads = (const float*)d_in[2];  // [64]
    const float* bs    = (const float*)d_in[3];  // [1]
    const float* noise = (const float*)d_in[4];  // [16384, 64]
    float* out = (float*)d_out;                  // [131072 idx | 131072 w | 64 loads | 1 bias]
    float* ws  = (float*)d_ws;
    float* ws_bias  = ws;
    float* ws_batch = ws + 64;
    f16_t* whi = (f16_t*)(ws + 128);             // 16384 frags x 8 halves = 256 KB
    f16_t* wlo = whi + (size_t)16384 * 8;        // another 256 KB

    prep_kernel<<<65, 256, 0, stream>>>(rw, loads, bs, ws_bias, ws_batch, whi, wlo,
                                        out + (size_t)NT * TK * 2 + NE);
    router_main<<<NT / 32, 512, 0, stream>>>(x, whi, wlo, noise, ws_bias, ws_batch, out);
    finalize_kernel<<<1, 64, 0, stream>>>(loads, ws_batch, out + (size_t)NT * TK * 2);
}

// Round 5
// 213.009 us; speedup vs baseline: 1.4355x; 1.0161x over previous
//
#include <hip/hip_runtime.h>
#include <math.h>

#define NT 16384
#define DIM 2048
#define NE 64
#define TK 8

typedef _Float16 f16_t;
typedef _Float16 half8 __attribute__((ext_vector_type(8)));
typedef float floatx16 __attribute__((ext_vector_type(16)));

// ---------------- Prep: W fp32 -> f16 hi/lo in 32x32x16 B-fragment order; block 64 = scalar chain ----------------
// B-frag layout (verified): lane holds B[n=lane&31][k=8*(lane>>5)+j], one 16B half8 per frag.
// Also zeroes ws_batch + ws_counter (workspace is re-poisoned by harness every iteration).
__global__ __launch_bounds__(256) void prep_kernel(const float* __restrict__ w,
                                                   const float* __restrict__ expert_loads,
                                                   const float* __restrict__ bias_strength,
                                                   float* __restrict__ ws_bias,
                                                   float* __restrict__ ws_batch,
                                                   unsigned int* __restrict__ ws_counter,
                                                   f16_t* __restrict__ whi,
                                                   f16_t* __restrict__ wlo,
                                                   float* __restrict__ out_bias_strength) {
    if (blockIdx.x == 64) {
        int e = threadIdx.x;
        if (e < 64) {
            float load = expert_loads[e];
            float s = load;
            #pragma unroll
            for (int off = 32; off >= 1; off >>= 1) s += __shfl_xor(s, off, 64);
            s = fmaxf(s, 1e-8f);
            float q = load / s;
            const float t = 1.0f / 64.0f;
            float kl = t * (logf(t) - logf(fmaxf(q, 1e-8f)));
            #pragma unroll
            for (int off = 32; off >= 1; off >>= 1) kl += __shfl_xor(kl, off, 64);
            float as = 1.0f / (1.0f + expf(-10.0f * kl));
            float nbs = 0.9f * bias_strength[0] + 0.1f * as;
            ws_bias[e] = tanhf((q - t) * 64.0f) * nbs;
            ws_batch[e] = 0.0f;
            if (e == 0) { out_bias_strength[0] = nbs; ws_counter[0] = 0u; }
        }
        return;
    }
    int idx = blockIdx.x * 256 + threadIdx.x;   // (c16, tile, lane)
    int lane = idx & 63;
    int tile = (idx >> 6) & 1;
    int c    = idx >> 7;
    int n = tile * 32 + (lane & 31);
    int k = c * 16 + (lane >> 5) * 8;
    const float* src = w + (size_t)n * DIM + k;
    float4 a = *(const float4*)src;
    float4 b = *(const float4*)(src + 4);
    float v[8] = {a.x, a.y, a.z, a.w, b.x, b.y, b.z, b.w};
    half8 h, l;
    #pragma unroll
    for (int j = 0; j < 8; ++j) {
        f16_t hh = (f16_t)v[j];
        h[j] = hh;
        l[j] = (f16_t)(v[j] - (float)hh);
    }
    *(half8*)(whi + (size_t)idx * 8) = h;
    *(half8*)(wlo + (size_t)idx * 8) = l;
}

// ---------------- Main: BARRIER-FREE wave-private split-f16 MFMA GEMM + noise + bias + top-8 + fused EMA --------
// 512 thr = 8 waves. Wave wv owns the CONTIGUOUS K-segment cols [wv*256, wv*256+256) -> staging is wave-private:
// each wave double-buffers its own 2 x 4KB LDS region (8 waves x 8KB = 64KB, overlaid by part[] afterwards).
// NO s_barrier in the K-loop: per-wave counted vmcnt(12) is the only sync. (Round-4 verified structure.)
// New this round: (1) top-8 parallelized 4 threads/token (scan-16 + 2-level bitonic shuffle merge, exact
// jax.lax.top_k tie semantics via total order (v desc, e asc)); (2) EMA finalize fused via returning-atomic
// ordering (NO __threadfence -- that cost ~90us in rounds 2/3): returning atomicAdd retires => performed at
// device-coherent point; wave-local vmcnt(0) orders it before the counter bump.
__global__ __launch_bounds__(512, 4) void router_main(const float* __restrict__ x,
                                                      const f16_t* __restrict__ whi,
                                                      const f16_t* __restrict__ wlo,
                                                      const float* __restrict__ noise,
                                                      const float* __restrict__ ws_bias,
                                                      float* __restrict__ ws_batch,
                                                      unsigned int* __restrict__ ws_counter,
                                                      const float* __restrict__ expert_loads,
                                                      float* __restrict__ out) {
    // 69,632 B: stage[8 waves][2 bufs][1024 f32] (65,536 B) overlaid by part[8][32][68] f32 afterwards
    __shared__ float smem[17408];
    __shared__ float bias_sh[64];
    __shared__ float loads_sh[64];
    __shared__ int last_flag;

    const int tid = threadIdx.x;
    const int wv  = tid >> 6;        // 0..7: owns cols [wv*256, wv*256+256)
    const int L   = tid & 63;
    const int r   = L & 31;          // A-frag row (token within tile)
    const int kh  = L >> 5;
    const int sw  = r & 7;           // per-lane swizzle key
    const int token0 = blockIdx.x * 32;

    if (tid < 64) { bias_sh[tid] = ws_bias[tid]; loads_sh[tid] = 0.0f; }

    // Noise prefetch: one float4/thread, held in VGPRs across the GEMM (reduce indexed to match).
    float4 nz = *(const float4*)(noise + (size_t)token0 * NE + tid * 4);

    const half8* whi8 = (const half8*)whi;
    const half8* wlo8 = (const half8*)wlo;

    floatx16 acc0, acc1;
    #pragma unroll
    for (int i = 0; i < 16; ++i) { acc0[i] = 0.0f; acc1[i] = 0.0f; }

    // Stage window S (32 rows x 32 cols of this wave's segment) into wave-private buffer S&1.
    // ldst is wave-uniform (gload_lds writes base + lane*16); gsrc carries the per-lane swizzle (T21).
    auto STAGE = [&](int S) {
        const int b_ = S & 1;
        #pragma unroll
        for (int q = 0; q < 4; ++q) {
            const float* gsrc = x + (size_t)(token0 + q * 8 + (L >> 3)) * DIM
                                  + wv * 256 + S * 32 + (((L & 7) ^ ((L >> 3) & 7)) << 2);
            float* ldst = (float*)(smem + wv * 2048 + b_ * 1024 + q * 256);
            __builtin_amdgcn_global_load_lds(
                (const __attribute__((address_space(1))) unsigned int*)gsrc,
                (__attribute__((address_space(3))) unsigned int*)ldst,
                16, 0, 0);
        }
    };

    STAGE(0);

    #pragma unroll
    for (int s = 0; s < 8; ++s) {
        // B fragments for this wave's two chunks of window s (L2-resident, 8 x 16B). Issued before STAGE(s+1)
        // so the compiler's pre-MFMA wait lands at vmcnt(4), keeping the prefetch in flight.
        half8 bf[8];
        {
            const int c0 = wv * 16 + s * 2;
            const int i0 = (c0 * 2) * 64 + L;
            const int i1 = ((c0 + 1) * 2) * 64 + L;
            bf[0] = whi8[i0];      bf[1] = whi8[i0 + 64];
            bf[2] = wlo8[i0];      bf[3] = wlo8[i0 + 64];
            bf[4] = whi8[i1];      bf[5] = whi8[i1 + 64];
            bf[6] = wlo8[i1];      bf[7] = wlo8[i1 + 64];
        }
        if (s < 7) {
            STAGE(s + 1);
            asm volatile("s_waitcnt vmcnt(12)" ::: "memory");  // window-s stage retired; 8 B-frag + 4 prefetch alive
        } else {
            asm volatile("s_waitcnt vmcnt(8)" ::: "memory");   // last window: only 8 B-frags newer
        }
        // NO barrier: this wave reads only its own buffer.

        const float* wb = smem + wv * 2048 + (s & 1) * 1024;
        #pragma unroll
        for (int cc = 0; cc < 2; ++cc) {
            const int u  = kh * 2 + cc * 4;            // even logical unit
            const int pu = (u ^ sw);
            float4 f0 = *(const float4*)(wb + r * 32 + (pu << 2));
            float4 f1 = *(const float4*)(wb + r * 32 + ((pu ^ 1) << 2));
            float v[8] = {f0.x, f0.y, f0.z, f0.w, f1.x, f1.y, f1.z, f1.w};
            half8 ah, al;
            #pragma unroll
            for (int j = 0; j < 8; ++j) {
                f16_t hh = (f16_t)v[j];              // RNE hi (verified numerics)
                ah[j] = hh;
                al[j] = (f16_t)(v[j] - (float)hh);   // RNE lo
            }
            acc0 = __builtin_amdgcn_mfma_f32_32x32x16_f16(ah, bf[cc * 4 + 0], acc0, 0, 0, 0);
            acc1 = __builtin_amdgcn_mfma_f32_32x32x16_f16(ah, bf[cc * 4 + 1], acc1, 0, 0, 0);
            acc0 = __builtin_amdgcn_mfma_f32_32x32x16_f16(al, bf[cc * 4 + 0], acc0, 0, 0, 0);
            acc1 = __builtin_amdgcn_mfma_f32_32x32x16_f16(al, bf[cc * 4 + 1], acc1, 0, 0, 0);
            acc0 = __builtin_amdgcn_mfma_f32_32x32x16_f16(ah, bf[cc * 4 + 2], acc0, 0, 0, 0);
            acc1 = __builtin_amdgcn_mfma_f32_32x32x16_f16(ah, bf[cc * 4 + 3], acc1, 0, 0, 0);
        }
    }

    __syncthreads();   // all waves done with stage region -> reuse as part[]

    // C/D layout (verified m74/m101): col=lane&31, row=(reg&3)+8*(reg>>2)+4*kh
    #pragma unroll
    for (int reg = 0; reg < 16; ++reg) {
        int row = (reg & 3) + 8 * (reg >> 2) + 4 * kh;
        smem[wv * 2176 + row * 68 + r]      = acc0[reg];
        smem[wv * 2176 + row * 68 + 32 + r] = acc1[reg];
    }
    __syncthreads();

    // Split-K reduce + noise + bias -> final logits into part[0]. Thread tid owns o = tid*4+j (matches nz).
    float nzv[4] = {nz.x, nz.y, nz.z, nz.w};
    #pragma unroll
    for (int j = 0; j < 4; ++j) {
        int o = tid * 4 + j;                 // 0..2047
        int t = o >> 6, e = o & 63;
        float sum = 0.0f;
        #pragma unroll
        for (int q = 0; q < 8; ++q) sum += smem[q * 2176 + t * 68 + e];
        sum += nzv[j] * 0.01f - bias_sh[e];
        smem[t * 68 + e] = sum;              // own slot; no cross-thread hazard
    }
    __syncthreads();

    // ---- Top-8: 4 threads per token. Total order key = (value desc, expert asc) -- keys unique, so this
    // reproduces jax.lax.top_k (ascending scan with strict '>') exactly. Each sub-thread scans 16 experts,
    // then 2-level merge: shuffle partner's sorted-8, bitonic keep-max + 12-CE merge (static indices only).
    if (tid < 128) {
        const int t = tid >> 2;              // token 0..31
        const int m = tid & 3;               // expert sub-range [m*16, m*16+16)
        float av[8]; int ai[8];
        #pragma unroll
        for (int j = 0; j < TK; ++j) { av[j] = -INFINITY; ai[j] = 0x7FFFFFFF; }
        const float* lg = smem + t * 68 + m * 16;
        float4 q0 = *(const float4*)(lg);
        float4 q1 = *(const float4*)(lg + 4);
        float4 q2 = *(const float4*)(lg + 8);
        float4 q3 = *(const float4*)(lg + 12);
        float cand[16] = {q0.x, q0.y, q0.z, q0.w, q1.x, q1.y, q1.z, q1.w,
                          q2.x, q2.y, q2.z, q2.w, q3.x, q3.y, q3.z, q3.w};
        #pragma unroll
        for (int e0 = 0; e0 < 16; ++e0) {
            float v = cand[e0]; int id = m * 16 + e0;
            #pragma unroll
            for (int j = 0; j < TK; ++j) {
                bool gt = v > av[j];                 // strict '>': earlier (lower) index stays ahead
                float nv = gt ? v : av[j];
                int   ni = gt ? id : ai[j];
                float ov = gt ? av[j] : v;
                int   oi = gt ? ai[j] : id;
                av[j] = nv; ai[j] = ni; v = ov; id = oi;
            }
        }
        // two merge levels: partner lane^1 (ranges 16 apart), then lane^2 (ranges 32 apart)
        #pragma unroll
        for (int lvl = 0; lvl < 2; ++lvl) {
            const int d = 1 << lvl;
            float pv[8]; int pi[8];
            #pragma unroll
            for (int j = 0; j < TK; ++j) {
                pv[j] = __shfl_xor(av[j], d, 64);
                pi[j] = __shfl_xor(ai[j], d, 64);
            }
            const bool iamA = ((m & d) == 0);        // A = list covering lower expert indices
            float Av[8], Bv[8]; int Ai[8], Bi[8];
            #pragma unroll
            for (int j = 0; j < TK; ++j) {
                Av[j] = iamA ? av[j] : pv[j];  Ai[j] = iamA ? ai[j] : pi[j];
                Bv[j] = iamA ? pv[j] : av[j];  Bi[j] = iamA ? pi[j] : ai[j];
            }
            // bitonic: c[i]=A[i], c[8+i]=B[7-i]; keep elementwise winner -> bitonic top-8
            #pragma unroll
            for (int j = 0; j < TK; ++j) {
                float bv = Bv[7 - j]; int bi = Bi[7 - j];
                bool w = (Av[j] > bv) || (Av[j] == bv && Ai[j] < bi);
                av[j] = w ? Av[j] : bv;
                ai[j] = w ? Ai[j] : bi;
            }
            // bitonic merge-8 desc: CE distances 4,2,1
            #pragma unroll
            for (int dd = 4; dd >= 1; dd >>= 1) {
                #pragma unroll
                for (int j = 0; j < TK; ++j) {
                    if ((j & dd) == 0) {
                        int k2 = j + dd;
                        bool w = (av[j] > av[k2]) || (av[j] == av[k2] && ai[j] < ai[k2]);
                        float lv = w ? av[j] : av[k2], hv = w ? av[k2] : av[j];
                        int   li = w ? ai[j] : ai[k2], hi_ = w ? ai[k2] : ai[j];
                        av[j] = lv; ai[j] = li; av[k2] = hv; ai[k2] = hi_;
                    }
                }
            }
        }
        if (m == 0) {
            float mx = av[0], ssum = 0.0f, wvv[TK];
            #pragma unroll
            for (int j = 0; j < TK; ++j) { wvv[j] = expf(av[j] - mx); ssum += wvv[j]; }
            float inv = 1.0f / ssum;
            size_t gt_ = (size_t)(token0 + t);
            #pragma unroll
            for (int j = 0; j < TK; ++j) {
                float wgt = wvv[j] * inv;
                out[gt_ * TK + j] = (float)ai[j];
                out[(size_t)NT * TK + gt_ * TK + j] = wgt;
                atomicAdd(&loads_sh[ai[j]], wgt);
            }
        }
    }
    __syncthreads();

    // ---- fused EMA finalize via returning-atomic ordering (no fence, no L2 writeback) ----
    if (tid < 64) {
        float old = atomicAdd(&ws_batch[tid], loads_sh[tid]);   // returning form -> performed at LLC on retire
        asm volatile("" :: "v"(old));                           // keep the returning variant live
    }
    if (tid == 0) {
        asm volatile("s_waitcnt vmcnt(0)" ::: "memory");        // wave 0's 64 atomics performed
        unsigned int prev = atomicAdd(ws_counter, 1u);
        last_flag = (prev == (unsigned int)(NT / 32 - 1)) ? 1 : 0;
    }
    __syncthreads();
    if (last_flag && tid < 64) {
        float bl = atomicAdd(&ws_batch[tid], 0.0f);             // coherent LLC read
        out[(size_t)NT * TK * 2 + tid] = 0.999f * expert_loads[tid] + 0.001f * (bl / (float)NT);
    }
}

extern "C" void kernel_launch(void* const* d_in, const int* in_sizes, int n_in,
                              void* d_out, int out_size, void* d_ws, size_t ws_size,
                              hipStream_t stream) {
    const float* x     = (const float*)d_in[0];  // [16384, 2048]
    const float* rw    = (const float*)d_in[1];  // [64, 2048]
    const float* loads = (const float*)d_in[2];  // [64]
    const float* bs    = (const float*)d_in[3];  // [1]
    const float* noise = (const float*)d_in[4];  // [16384, 64]
    float* out = (float*)d_out;                  // [131072 idx | 131072 w | 64 loads | 1 bias]
    float* ws  = (float*)d_ws;
    float* ws_bias  = ws;                        // [64]
    float* ws_batch = ws + 64;                   // [64]
    unsigned int* ws_counter = (unsigned int*)(ws + 128);
    f16_t* whi = (f16_t*)(ws + 160);             // 16384 frags x 8 halves = 256 KB (16B aligned)
    f16_t* wlo = whi + (size_t)16384 * 8;        // another 256 KB

    prep_kernel<<<65, 256, 0, stream>>>(rw, loads, bs, ws_bias, ws_batch, ws_counter, whi, wlo,
                                        out + (size_t)NT * TK * 2 + NE);
    router_main<<<NT / 32, 512, 0, stream>>>(x, whi, wlo, noise, ws_bias, ws_batch, ws_counter,
                                             loads, out);
}